// Round 2
// baseline (456.322 us; speedup 1.0000x reference)
//
#include <hip/hip_runtime.h>

// GCN 3-layer (PyG GCNConv: self-loops + D^-1/2 A D^-1/2).
// R1 change: replace {k_count + k_fill} (117us, 107MB write-amplified scatter)
// with {k_partition (bucket edges by dst>>12 via LDS multisplit, fused deg
// count) + k_fillB (bucket-local CSR fill -> scatter confined to ~260KB,
// L2-resident, ~1x write amplification)}.

#define SHIFT 12  // nodes per bucket = 4096 (host verifies B<=32)

__global__ __launch_bounds__(256) void k_partition(
    const int* __restrict__ src, const int* __restrict__ dst, int E,
    int* __restrict__ deg, int* __restrict__ bcur,
    uint2* __restrict__ pairs, int cap) {
    __shared__ int cnt[32];
    __shared__ int gbase[32];
    int t = threadIdx.x;
    int base = blockIdx.x * 1024;
    if (t < 32) cnt[t] = 0;
    __syncthreads();
    int s[4], d[4], r[4], b[4];
    #pragma unroll
    for (int j = 0; j < 4; ++j) {
        int e = base + j * 256 + t;           // coalesced per j
        if (e < E) {
            s[j] = src[e]; d[j] = dst[e];
            b[j] = d[j] >> SHIFT;
            atomicAdd(&deg[d[j]], 1);         // deg: 400KB, L2-resident
            r[j] = atomicAdd(&cnt[b[j]], 1);  // local rank within block+bucket
        } else b[j] = -1;
    }
    __syncthreads();
    if (t < 32) gbase[t] = cnt[t] ? atomicAdd(&bcur[t], cnt[t]) : 0;
    __syncthreads();
    #pragma unroll
    for (int j = 0; j < 4; ++j) {
        if (b[j] >= 0) {
            int idx = gbase[b[j]] + r[j];
            if (idx < cap)  // capacity guard (never hit: cap = 1.25*avg + 1K)
                pairs[(size_t)b[j] * cap + idx] =
                    make_uint2((unsigned)s[j], (unsigned)d[j]);
        }
    }
}

// Per-bucket CSR fill: rowptr/cursor/col windows for one bucket span ~260KB
// -> all L2-resident -> no write amplification.
__global__ __launch_bounds__(256) void k_fillB(
    const uint2* __restrict__ pairs, const int* __restrict__ bcnt,
    int cap, int BPB, const int* __restrict__ rowptr,
    int* __restrict__ cursor, int* __restrict__ col) {
    int b = blockIdx.x / BPB, sub = blockIdx.x % BPB;
    int n = bcnt[b];
    const uint2* pb = pairs + (size_t)b * cap;
    for (int i = sub * 256 + threadIdx.x; i < n; i += BPB * 256) {
        uint2 e = pb[i];
        int p = atomicAdd(&cursor[e.y], 1);
        col[rowptr[e.y] + p] = (int)e.x;
    }
}

// Block-local exclusive scan (256 elems/block) -> rowptr partial + block sums
__global__ void k_scan1(const int* __restrict__ deg, int N,
                        int* __restrict__ rowptr, int* __restrict__ bsum) {
    __shared__ int lds[256];
    int t = threadIdx.x;
    int i = blockIdx.x * 256 + t;
    int v = (i < N) ? deg[i] : 0;
    lds[t] = v; __syncthreads();
    #pragma unroll
    for (int off = 1; off < 256; off <<= 1) {
        int tmp = (t >= off) ? lds[t - off] : 0; __syncthreads();
        lds[t] += tmp; __syncthreads();
    }
    if (i < N) rowptr[i] = lds[t] - v;
    if (t == 255) bsum[blockIdx.x] = lds[255];
}

__global__ void k_scan2(const int* __restrict__ bsum, int nb, int* __restrict__ boff) {
    __shared__ int lds[1024];
    int t = threadIdx.x;
    int v = (t < nb) ? bsum[t] : 0;
    lds[t] = v; __syncthreads();
    #pragma unroll
    for (int off = 1; off < 1024; off <<= 1) {
        int tmp = (t >= off) ? lds[t - off] : 0; __syncthreads();
        lds[t] += tmp; __syncthreads();
    }
    if (t < nb) boff[t] = lds[t] - v;
    if (t == 0) boff[nb] = lds[1023];
}

__global__ void k_scan3(const int* __restrict__ boff, int N, int nb,
                        int* __restrict__ rowptr, int* __restrict__ deg,
                        float* __restrict__ dinv) {
    int i = blockIdx.x * blockDim.x + threadIdx.x;
    if (i < N) {
        rowptr[i] += boff[i >> 8];
        dinv[i] = rsqrtf((float)deg[i] + 1.0f);
        deg[i] = 0;                            // becomes cursor for k_fillB
    } else if (i == N) {
        rowptr[N] = boff[nb];
    }
}

// Layer-1 GEMM collapses: hw1[n,d] = dinv[n]*(x[n]*W1[0,d] + c[d])
__global__ void k_layer1(const float* __restrict__ x, const float* __restrict__ delta,
                         const float* __restrict__ W1, const float* __restrict__ dinv,
                         float* __restrict__ hw, int N) {
    int idx = blockIdx.x * blockDim.x + threadIdx.x;
    if (idx >= N * 64) return;
    int n = idx >> 6, d = idx & 63;
    float c = delta[0] * W1[64 + d] + delta[1] * W1[128 + d] +
              delta[2] * W1[192 + d] + delta[3] * W1[256 + d];
    hw[idx] = dinv[n] * fmaf(x[n], W1[d], c);
}

// Wave-per-node aggregation: lane = feature d. Coalesced 256B row per edge.
__device__ __forceinline__ float agg_row(const float* __restrict__ hw_in,
                                         const int* __restrict__ col,
                                         int rs, int re, int lane, float self) {
    float acc = self;
    for (int base = rs; base < re; base += 64) {
        int cnt = min(64, re - base);
        int s = (lane < cnt) ? col[base + lane] : 0;
        int j = 0;
        for (; j + 4 <= cnt; j += 4) {
            int s0 = __shfl(s, j), s1 = __shfl(s, j + 1);
            int s2 = __shfl(s, j + 2), s3 = __shfl(s, j + 3);
            float v0 = hw_in[(size_t)s0 * 64 + lane];
            float v1 = hw_in[(size_t)s1 * 64 + lane];
            float v2 = hw_in[(size_t)s2 * 64 + lane];
            float v3 = hw_in[(size_t)s3 * 64 + lane];
            acc += (v0 + v1) + (v2 + v3);
        }
        for (; j < cnt; ++j)
            acc += hw_in[(size_t)__shfl(s, j) * 64 + lane];
    }
    return acc;
}

__global__ __launch_bounds__(256) void k_agg_gemm64(
    const float* __restrict__ hw_in, const int* __restrict__ rowptr,
    const int* __restrict__ col, const float* __restrict__ dinv,
    const float* __restrict__ bias, const float* __restrict__ W,
    float* __restrict__ hw_out, int N) {
    __shared__ float rowbuf[4][64];
    int lane = threadIdx.x & 63, wave = threadIdx.x >> 6;
    float Wreg[64];
    #pragma unroll
    for (int k = 0; k < 64; ++k) Wreg[k] = W[k * 64 + lane];
    float b = bias[lane];
    int gw = blockIdx.x * 4 + wave;
    int stride = gridDim.x * 4;
    for (int n = gw; n < N; n += stride) {
        float self = hw_in[(size_t)n * 64 + lane];
        int rs = rowptr[n], re = rowptr[n + 1];
        float acc = agg_row(hw_in, col, rs, re, lane, self);
        float dn = dinv[n];
        float t = fmaxf(fmaf(dn, acc, b), 0.0f);
        rowbuf[wave][lane] = t;
        __builtin_amdgcn_wave_barrier();
        float o = 0.f;
        const float4* rb = (const float4*)(&rowbuf[wave][0]);
        #pragma unroll
        for (int k4 = 0; k4 < 16; ++k4) {
            float4 tv = rb[k4];
            o = fmaf(tv.x, Wreg[4 * k4 + 0], o);
            o = fmaf(tv.y, Wreg[4 * k4 + 1], o);
            o = fmaf(tv.z, Wreg[4 * k4 + 2], o);
            o = fmaf(tv.w, Wreg[4 * k4 + 3], o);
        }
        hw_out[(size_t)n * 64 + lane] = dn * o;
    }
}

__global__ __launch_bounds__(256) void k_agg_out3(
    const float* __restrict__ hw_in, const int* __restrict__ rowptr,
    const int* __restrict__ col, const float* __restrict__ dinv,
    const float* __restrict__ bias, const float* __restrict__ W3,
    float4* __restrict__ hw3, int N) {
    int lane = threadIdx.x & 63, wave = threadIdx.x >> 6;
    float w0 = W3[lane * 3 + 0], w1 = W3[lane * 3 + 1], w2 = W3[lane * 3 + 2];
    float b = bias[lane];
    int gw = blockIdx.x * 4 + wave;
    int stride = gridDim.x * 4;
    for (int n = gw; n < N; n += stride) {
        float self = hw_in[(size_t)n * 64 + lane];
        int rs = rowptr[n], re = rowptr[n + 1];
        float acc = agg_row(hw_in, col, rs, re, lane, self);
        float dn = dinv[n];
        float t = fmaxf(fmaf(dn, acc, b), 0.0f);
        float p0 = t * w0, p1 = t * w1, p2 = t * w2;
        #pragma unroll
        for (int off = 32; off; off >>= 1) {
            p0 += __shfl_xor(p0, off);
            p1 += __shfl_xor(p1, off);
            p2 += __shfl_xor(p2, off);
        }
        if (lane == 0) hw3[n] = make_float4(dn * p0, dn * p1, dn * p2, 0.f);
    }
}

__global__ __launch_bounds__(256) void k_final(
    const float4* __restrict__ hw3, const int* __restrict__ rowptr,
    const int* __restrict__ col, const float* __restrict__ dinv,
    const float* __restrict__ b3, const float* __restrict__ x,
    const float* __restrict__ pos, float* __restrict__ out, int N) {
    int lane = threadIdx.x & 63, wave = threadIdx.x >> 6;
    int n = blockIdx.x * 4 + wave;
    if (n >= N) return;
    int rs = rowptr[n], re = rowptr[n + 1];
    float a0 = 0.f, a1 = 0.f, a2 = 0.f;
    for (int i = rs + lane; i < re; i += 64) {
        float4 v = hw3[col[i]];
        a0 += v.x; a1 += v.y; a2 += v.z;
    }
    #pragma unroll
    for (int off = 32; off; off >>= 1) {
        a0 += __shfl_xor(a0, off);
        a1 += __shfl_xor(a1, off);
        a2 += __shfl_xor(a2, off);
    }
    if (lane == 0) {
        float4 sv = hw3[n];
        a0 += sv.x; a1 += sv.y; a2 += sv.z;
        float dn = dinv[n];
        float o0 = fmaf(dn, a0, b3[0]);
        float o1 = fmaf(dn, a1, b3[1]);
        float o2 = fmaf(dn, a2, b3[2]);
        out[n] = x[n] + o2;
        out[N + 2 * n]     = pos[2 * n]     + o0;
        out[N + 2 * n + 1] = pos[2 * n + 1] + o1;
    }
}

extern "C" void kernel_launch(void* const* d_in, const int* in_sizes, int n_in,
                              void* d_out, int out_size, void* d_ws, size_t ws_size,
                              hipStream_t stream) {
    const float* x     = (const float*)d_in[0];
    const float* pos   = (const float*)d_in[1];
    const float* delta = (const float*)d_in[2];
    const int*   ei    = (const int*)  d_in[3];
    const float* W1    = (const float*)d_in[4];
    const float* b1    = (const float*)d_in[5];
    const float* W2    = (const float*)d_in[6];
    const float* b2    = (const float*)d_in[7];
    const float* W3    = (const float*)d_in[8];
    const float* b3    = (const float*)d_in[9];
    int N = in_sizes[0];
    int E = in_sizes[3] / 2;
    const int* src = ei;
    const int* dst = ei + E;

    char* p = (char*)d_ws;
    auto alloc = [&](size_t bytes) {
        char* r = p; p += (bytes + 255) & ~(size_t)255; return r;
    };
    int*   deg    = (int*)  alloc((size_t)N * 4);   // then reused as cursor
    int*   bcur   = (int*)  alloc(32 * 4);          // adjacent to deg: one memset
    int*   rowptr = (int*)  alloc((size_t)(N + 1) * 4);
    int nb1 = (N + 255) / 256;
    int*   bsum   = (int*)  alloc((size_t)nb1 * 4);
    int*   boff   = (int*)  alloc((size_t)(nb1 + 1) * 4);
    float* dinv   = (float*)alloc((size_t)N * 4);
    int*   col    = (int*)  alloc((size_t)E * 4);
    float* hw_a   = (float*)alloc((size_t)N * 64 * 4);
    float* hw_b   = (float*)alloc((size_t)N * 64 * 4);
    float4* hw3   = (float4*)hw_a;                  // hw_a dead after layer2
    uint2*  pairs = (uint2*)hw_b;                   // hw_b dead until agg_gemm64

    int B   = (N + (1 << SHIFT) - 1) >> SHIFT;      // 25 buckets for N=100K
    int avg = (int)(((long long)E << SHIFT) / N);
    int cap = avg + avg / 4 + 1024;                 // ~82K; 25*cap*8B = 16.4MB < hw_b
    // assumption check: B<=32 and pairs fits hw_b (holds for this problem size)

    hipMemsetAsync(deg, 0, (size_t)((char*)bcur - (char*)deg) + 32 * 4, stream);
    k_partition<<<(E + 1023) / 1024, 256, 0, stream>>>(src, dst, E, deg, bcur, pairs, cap);
    k_scan1<<<nb1, 256, 0, stream>>>(deg, N, rowptr, bsum);
    k_scan2<<<1, 1024, 0, stream>>>(bsum, nb1, boff);
    k_scan3<<<(N + 256) / 256, 256, 0, stream>>>(boff, N, nb1, rowptr, deg, dinv);
    const int BPB = 80;                             // blocks per bucket
    k_fillB<<<B * BPB, 256, 0, stream>>>(pairs, bcur, cap, BPB, rowptr, deg, col);
    k_layer1<<<(N * 64 + 255) / 256, 256, 0, stream>>>(x, delta, W1, dinv, hw_a, N);
    k_agg_gemm64<<<2048, 256, 0, stream>>>(hw_a, rowptr, col, dinv, b1, W2, hw_b, N);
    k_agg_out3<<<2048, 256, 0, stream>>>(hw_b, rowptr, col, dinv, b2, W3, hw3, N);
    k_final<<<(N + 3) / 4, 256, 0, stream>>>(hw3, rowptr, col, dinv, b3, x, pos,
                                             (float*)d_out, N);
}

// Round 3
// 315.672 us; speedup vs baseline: 1.4456x; 1.4456x over previous
//
#include <hip/hip_runtime.h>

// GCN 3-layer (PyG GCNConv: self-loops + D^-1/2 A D^-1/2).
// R2 change: ZERO per-edge global atomics. R1/R2 profiling showed each global
// atomicAdd costs a 64B fabric RMW (1.6M x 64B = 102MB WRITE_SIZE, ~120us) --
// per-XCD L2s can't own device-scope atomics. New CSR build: bucketed counting
// sort (512 dst-nodes/bucket, edge packed as src<<9|dstlow in one uint);
// all per-edge atomics are LDS atomics; only ~77K global bucket-claim atomics.

#define SHIFT 9
#define BW_ (1 << SHIFT)      // 512 nodes per bucket
#define ITEMS 16              // edges per thread in k_partition

__global__ __launch_bounds__(256) void k_partition(
    const int* __restrict__ src, const int* __restrict__ dst, int E,
    int* __restrict__ bcur, unsigned* __restrict__ words, int cap) {
    __shared__ int cnt[256];
    __shared__ int gbase[256];
    int t = threadIdx.x;
    int base = blockIdx.x * (256 * ITEMS);
    cnt[t] = 0;
    __syncthreads();
    unsigned w[ITEMS]; int b[ITEMS], r[ITEMS];
    #pragma unroll
    for (int j = 0; j < ITEMS; ++j) {
        int e = base + j * 256 + t;              // coalesced per j
        if (e < E) {
            int d = dst[e], s = src[e];
            b[j] = d >> SHIFT;
            w[j] = ((unsigned)s << SHIFT) | (unsigned)(d & (BW_ - 1));
            r[j] = atomicAdd(&cnt[b[j]], 1);     // LDS atomic
        } else b[j] = -1;
    }
    __syncthreads();
    int c = cnt[t];
    gbase[t] = c ? atomicAdd(&bcur[t], c) : 0;   // ~196 global atomics/block
    __syncthreads();
    #pragma unroll
    for (int j = 0; j < ITEMS; ++j) {
        if (b[j] >= 0) {
            int idx = gbase[b[j]] + r[j];
            if (idx < cap)                        // safety; cap = 2x mean
                words[(size_t)b[j] * cap + idx] = w[j];
        }
    }
}

// One block per bucket: LDS histogram -> coalesced deg write (no memset needed).
__global__ __launch_bounds__(512) void k_hist(
    const unsigned* __restrict__ words, const int* __restrict__ bcnt, int cap,
    int* __restrict__ deg, int N) {
    __shared__ int h[BW_];
    int b = blockIdx.x, t = threadIdx.x;
    h[t] = 0;
    __syncthreads();
    int n = min(bcnt[b], cap);
    const unsigned* wb = words + (size_t)b * cap;
    for (int i = t; i < n; i += 512)
        atomicAdd(&h[wb[i] & (BW_ - 1)], 1);     // LDS atomic
    __syncthreads();
    int node = b * BW_ + t;
    if (node < N) deg[node] = h[t];
}

// One block per bucket: LDS cursors seeded from rowptr; col scatter confined
// to ~32KB window owned by this block -> ~1x write amplification.
__global__ __launch_bounds__(512) void k_place(
    const unsigned* __restrict__ words, const int* __restrict__ bcnt, int cap,
    const int* __restrict__ rowptr, int* __restrict__ col, int N) {
    __shared__ int cur[BW_];
    int b = blockIdx.x, t = threadIdx.x;
    int node = b * BW_ + t;
    cur[t] = (node < N) ? rowptr[node] : 0;
    __syncthreads();
    int n = min(bcnt[b], cap);
    const unsigned* wb = words + (size_t)b * cap;
    for (int i = t; i < n; i += 512) {
        unsigned w = wb[i];
        int p = atomicAdd(&cur[w & (BW_ - 1)], 1);  // LDS atomic
        col[p] = (int)(w >> SHIFT);
    }
}

// Block-local exclusive scan (256 elems/block) -> rowptr partial + block sums
__global__ void k_scan1(const int* __restrict__ deg, int N,
                        int* __restrict__ rowptr, int* __restrict__ bsum) {
    __shared__ int lds[256];
    int t = threadIdx.x;
    int i = blockIdx.x * 256 + t;
    int v = (i < N) ? deg[i] : 0;
    lds[t] = v; __syncthreads();
    #pragma unroll
    for (int off = 1; off < 256; off <<= 1) {
        int tmp = (t >= off) ? lds[t - off] : 0; __syncthreads();
        lds[t] += tmp; __syncthreads();
    }
    if (i < N) rowptr[i] = lds[t] - v;
    if (t == 255) bsum[blockIdx.x] = lds[255];
}

__global__ void k_scan2(const int* __restrict__ bsum, int nb, int* __restrict__ boff) {
    __shared__ int lds[1024];
    int t = threadIdx.x;
    int v = (t < nb) ? bsum[t] : 0;
    lds[t] = v; __syncthreads();
    #pragma unroll
    for (int off = 1; off < 1024; off <<= 1) {
        int tmp = (t >= off) ? lds[t - off] : 0; __syncthreads();
        lds[t] += tmp; __syncthreads();
    }
    if (t < nb) boff[t] = lds[t] - v;
    if (t == 0) boff[nb] = lds[1023];
}

__global__ void k_scan3(const int* __restrict__ boff, int N, int nb,
                        int* __restrict__ rowptr, const int* __restrict__ deg,
                        float* __restrict__ dinv) {
    int i = blockIdx.x * blockDim.x + threadIdx.x;
    if (i < N) {
        rowptr[i] += boff[i >> 8];
        dinv[i] = rsqrtf((float)deg[i] + 1.0f);
    } else if (i == N) {
        rowptr[N] = boff[nb];
    }
}

// Layer-1 GEMM collapses: hw1[n,d] = dinv[n]*(x[n]*W1[0,d] + c[d])
__global__ void k_layer1(const float* __restrict__ x, const float* __restrict__ delta,
                         const float* __restrict__ W1, const float* __restrict__ dinv,
                         float* __restrict__ hw, int N) {
    int idx = blockIdx.x * blockDim.x + threadIdx.x;
    if (idx >= N * 64) return;
    int n = idx >> 6, d = idx & 63;
    float c = delta[0] * W1[64 + d] + delta[1] * W1[128 + d] +
              delta[2] * W1[192 + d] + delta[3] * W1[256 + d];
    hw[idx] = dinv[n] * fmaf(x[n], W1[d], c);
}

// Wave-per-node aggregation: lane = feature d. Coalesced 256B row per edge.
__device__ __forceinline__ float agg_row(const float* __restrict__ hw_in,
                                         const int* __restrict__ col,
                                         int rs, int re, int lane, float self) {
    float acc = self;
    for (int base = rs; base < re; base += 64) {
        int cnt = min(64, re - base);
        int s = (lane < cnt) ? col[base + lane] : 0;
        int j = 0;
        for (; j + 4 <= cnt; j += 4) {
            int s0 = __shfl(s, j), s1 = __shfl(s, j + 1);
            int s2 = __shfl(s, j + 2), s3 = __shfl(s, j + 3);
            float v0 = hw_in[(size_t)s0 * 64 + lane];
            float v1 = hw_in[(size_t)s1 * 64 + lane];
            float v2 = hw_in[(size_t)s2 * 64 + lane];
            float v3 = hw_in[(size_t)s3 * 64 + lane];
            acc += (v0 + v1) + (v2 + v3);
        }
        for (; j < cnt; ++j)
            acc += hw_in[(size_t)__shfl(s, j) * 64 + lane];
    }
    return acc;
}

__global__ __launch_bounds__(256) void k_agg_gemm64(
    const float* __restrict__ hw_in, const int* __restrict__ rowptr,
    const int* __restrict__ col, const float* __restrict__ dinv,
    const float* __restrict__ bias, const float* __restrict__ W,
    float* __restrict__ hw_out, int N) {
    __shared__ float rowbuf[4][64];
    int lane = threadIdx.x & 63, wave = threadIdx.x >> 6;
    float Wreg[64];
    #pragma unroll
    for (int k = 0; k < 64; ++k) Wreg[k] = W[k * 64 + lane];
    float b = bias[lane];
    int gw = blockIdx.x * 4 + wave;
    int stride = gridDim.x * 4;
    for (int n = gw; n < N; n += stride) {
        float self = hw_in[(size_t)n * 64 + lane];
        int rs = rowptr[n], re = rowptr[n + 1];
        float acc = agg_row(hw_in, col, rs, re, lane, self);
        float dn = dinv[n];
        float t = fmaxf(fmaf(dn, acc, b), 0.0f);
        rowbuf[wave][lane] = t;
        __builtin_amdgcn_wave_barrier();
        float o = 0.f;
        const float4* rb = (const float4*)(&rowbuf[wave][0]);
        #pragma unroll
        for (int k4 = 0; k4 < 16; ++k4) {
            float4 tv = rb[k4];
            o = fmaf(tv.x, Wreg[4 * k4 + 0], o);
            o = fmaf(tv.y, Wreg[4 * k4 + 1], o);
            o = fmaf(tv.z, Wreg[4 * k4 + 2], o);
            o = fmaf(tv.w, Wreg[4 * k4 + 3], o);
        }
        hw_out[(size_t)n * 64 + lane] = dn * o;
    }
}

__global__ __launch_bounds__(256) void k_agg_out3(
    const float* __restrict__ hw_in, const int* __restrict__ rowptr,
    const int* __restrict__ col, const float* __restrict__ dinv,
    const float* __restrict__ bias, const float* __restrict__ W3,
    float4* __restrict__ hw3, int N) {
    int lane = threadIdx.x & 63, wave = threadIdx.x >> 6;
    float w0 = W3[lane * 3 + 0], w1 = W3[lane * 3 + 1], w2 = W3[lane * 3 + 2];
    float b = bias[lane];
    int gw = blockIdx.x * 4 + wave;
    int stride = gridDim.x * 4;
    for (int n = gw; n < N; n += stride) {
        float self = hw_in[(size_t)n * 64 + lane];
        int rs = rowptr[n], re = rowptr[n + 1];
        float acc = agg_row(hw_in, col, rs, re, lane, self);
        float dn = dinv[n];
        float t = fmaxf(fmaf(dn, acc, b), 0.0f);
        float p0 = t * w0, p1 = t * w1, p2 = t * w2;
        #pragma unroll
        for (int off = 32; off; off >>= 1) {
            p0 += __shfl_xor(p0, off);
            p1 += __shfl_xor(p1, off);
            p2 += __shfl_xor(p2, off);
        }
        if (lane == 0) hw3[n] = make_float4(dn * p0, dn * p1, dn * p2, 0.f);
    }
}

__global__ __launch_bounds__(256) void k_final(
    const float4* __restrict__ hw3, const int* __restrict__ rowptr,
    const int* __restrict__ col, const float* __restrict__ dinv,
    const float* __restrict__ b3, const float* __restrict__ x,
    const float* __restrict__ pos, float* __restrict__ out, int N) {
    int lane = threadIdx.x & 63, wave = threadIdx.x >> 6;
    int n = blockIdx.x * 4 + wave;
    if (n >= N) return;
    int rs = rowptr[n], re = rowptr[n + 1];
    float a0 = 0.f, a1 = 0.f, a2 = 0.f;
    for (int i = rs + lane; i < re; i += 64) {
        float4 v = hw3[col[i]];
        a0 += v.x; a1 += v.y; a2 += v.z;
    }
    #pragma unroll
    for (int off = 32; off; off >>= 1) {
        a0 += __shfl_xor(a0, off);
        a1 += __shfl_xor(a1, off);
        a2 += __shfl_xor(a2, off);
    }
    if (lane == 0) {
        float4 sv = hw3[n];
        a0 += sv.x; a1 += sv.y; a2 += sv.z;
        float dn = dinv[n];
        float o0 = fmaf(dn, a0, b3[0]);
        float o1 = fmaf(dn, a1, b3[1]);
        float o2 = fmaf(dn, a2, b3[2]);
        out[n] = x[n] + o2;
        out[N + 2 * n]     = pos[2 * n]     + o0;
        out[N + 2 * n + 1] = pos[2 * n + 1] + o1;
    }
}

extern "C" void kernel_launch(void* const* d_in, const int* in_sizes, int n_in,
                              void* d_out, int out_size, void* d_ws, size_t ws_size,
                              hipStream_t stream) {
    const float* x     = (const float*)d_in[0];
    const float* pos   = (const float*)d_in[1];
    const float* delta = (const float*)d_in[2];
    const int*   ei    = (const int*)  d_in[3];
    const float* W1    = (const float*)d_in[4];
    const float* b1    = (const float*)d_in[5];
    const float* W2    = (const float*)d_in[6];
    const float* b2    = (const float*)d_in[7];
    const float* W3    = (const float*)d_in[8];
    const float* b3    = (const float*)d_in[9];
    int N = in_sizes[0];
    int E = in_sizes[3] / 2;
    const int* src = ei;
    const int* dst = ei + E;

    char* p = (char*)d_ws;
    auto alloc = [&](size_t bytes) {
        char* r = p; p += (bytes + 255) & ~(size_t)255; return r;
    };
    int*   deg    = (int*)  alloc((size_t)N * 4);
    int*   bcur   = (int*)  alloc(256 * 4);
    int*   rowptr = (int*)  alloc((size_t)(N + 1) * 4);
    int nb1 = (N + 255) / 256;
    int*   bsum   = (int*)  alloc((size_t)nb1 * 4);
    int*   boff   = (int*)  alloc((size_t)(nb1 + 1) * 4);
    float* dinv   = (float*)alloc((size_t)N * 4);
    int*   col    = (int*)  alloc((size_t)E * 4);
    float* hw_a   = (float*)alloc((size_t)N * 64 * 4);
    float* hw_b   = (float*)alloc((size_t)N * 64 * 4);
    float4*   hw3   = (float4*)hw_a;    // hw_a dead after layer2
    unsigned* words = (unsigned*)hw_b;  // hw_b dead until agg_gemm64

    int B   = (N + BW_ - 1) >> SHIFT;   // 196 buckets for N=100K (<=256)
    int cap = 2 * (E / B) + 1024;       // ~17.3K; B*cap*4B = 13.6MB < hw_b
    int npb = (E + (256 * ITEMS) - 1) / (256 * ITEMS);

    hipMemsetAsync(bcur, 0, 256 * 4, stream);   // only 1KB of memset now
    k_partition<<<npb, 256, 0, stream>>>(src, dst, E, bcur, words, cap);
    k_hist<<<B, 512, 0, stream>>>(words, bcur, cap, deg, N);
    k_scan1<<<nb1, 256, 0, stream>>>(deg, N, rowptr, bsum);
    k_scan2<<<1, 1024, 0, stream>>>(bsum, nb1, boff);
    k_scan3<<<(N + 256) / 256, 256, 0, stream>>>(boff, N, nb1, rowptr, deg, dinv);
    k_place<<<B, 512, 0, stream>>>(words, bcur, cap, rowptr, col, N);
    k_layer1<<<(N * 64 + 255) / 256, 256, 0, stream>>>(x, delta, W1, dinv, hw_a, N);
    k_agg_gemm64<<<2048, 256, 0, stream>>>(hw_a, rowptr, col, dinv, b1, W2, hw_b, N);
    k_agg_out3<<<2048, 256, 0, stream>>>(hw_b, rowptr, col, dinv, b2, W3, hw3, N);
    k_final<<<(N + 3) / 4, 256, 0, stream>>>(hw3, rowptr, col, dinv, b3, x, pos,
                                             (float*)d_out, N);
}

// Round 5
// 280.182 us; speedup vs baseline: 1.6287x; 1.1267x over previous
//
#include <hip/hip_runtime.h>

// GCN 3-layer (PyG GCNConv: self-loops + D^-1/2 A D^-1/2).
// R3 change (resubmitted R4 after acquisition timeout): hw features stored as
// packed bf16x2 (uint per feature pair, pre-scaled by dinv) -> halves gather
// traffic and footprint. Aggregation processes 2 edges per load instruction
// (lane half = edge parity, lane&31 = feature pair), fp32 accumulate, combine
// via shfl_xor(32). __launch_bounds__(256,4) so Wreg[64] stays in VGPRs (R3
// showed 48 VGPRs = compiler rematerialized W).

#define SHIFT 9
#define BW_ (1 << SHIFT)      // 512 nodes per bucket
#define ITEMS 16              // edges per thread in k_partition

__device__ __forceinline__ float blo(unsigned w) { return __uint_as_float(w << 16); }
__device__ __forceinline__ float bhi(unsigned w) { return __uint_as_float(w & 0xffff0000u); }
__device__ __forceinline__ unsigned packbf(float a, float b) {
    unsigned ua = __float_as_uint(a), ub = __float_as_uint(b);
    ua = (ua + 0x7fffu + ((ua >> 16) & 1u)) >> 16;         // RN-even
    ub = (ub + 0x7fffu + ((ub >> 16) & 1u)) & 0xffff0000u;
    return ua | ub;
}

__global__ __launch_bounds__(256) void k_partition(
    const int* __restrict__ src, const int* __restrict__ dst, int E,
    int* __restrict__ bcur, unsigned* __restrict__ words, int cap) {
    __shared__ int cnt[256];
    __shared__ int gbase[256];
    int t = threadIdx.x;
    int base = blockIdx.x * (256 * ITEMS);
    cnt[t] = 0;
    __syncthreads();
    unsigned w[ITEMS]; int b[ITEMS], r[ITEMS];
    #pragma unroll
    for (int j = 0; j < ITEMS; ++j) {
        int e = base + j * 256 + t;
        if (e < E) {
            int d = dst[e], s = src[e];
            b[j] = d >> SHIFT;
            w[j] = ((unsigned)s << SHIFT) | (unsigned)(d & (BW_ - 1));
            r[j] = atomicAdd(&cnt[b[j]], 1);     // LDS atomic
        } else b[j] = -1;
    }
    __syncthreads();
    int c = cnt[t];
    gbase[t] = c ? atomicAdd(&bcur[t], c) : 0;
    __syncthreads();
    #pragma unroll
    for (int j = 0; j < ITEMS; ++j) {
        if (b[j] >= 0) {
            int idx = gbase[b[j]] + r[j];
            if (idx < cap)
                words[(size_t)b[j] * cap + idx] = w[j];
        }
    }
}

__global__ __launch_bounds__(512) void k_hist(
    const unsigned* __restrict__ words, const int* __restrict__ bcnt, int cap,
    int* __restrict__ deg, int N) {
    __shared__ int h[BW_];
    int b = blockIdx.x, t = threadIdx.x;
    h[t] = 0;
    __syncthreads();
    int n = min(bcnt[b], cap);
    const unsigned* wb = words + (size_t)b * cap;
    for (int i = t; i < n; i += 512)
        atomicAdd(&h[wb[i] & (BW_ - 1)], 1);
    __syncthreads();
    int node = b * BW_ + t;
    if (node < N) deg[node] = h[t];
}

__global__ __launch_bounds__(512) void k_place(
    const unsigned* __restrict__ words, const int* __restrict__ bcnt, int cap,
    const int* __restrict__ rowptr, int* __restrict__ col, int N) {
    __shared__ int cur[BW_];
    int b = blockIdx.x, t = threadIdx.x;
    int node = b * BW_ + t;
    cur[t] = (node < N) ? rowptr[node] : 0;
    __syncthreads();
    int n = min(bcnt[b], cap);
    const unsigned* wb = words + (size_t)b * cap;
    for (int i = t; i < n; i += 512) {
        unsigned w = wb[i];
        int p = atomicAdd(&cur[w & (BW_ - 1)], 1);
        col[p] = (int)(w >> SHIFT);
    }
}

__global__ void k_scan1(const int* __restrict__ deg, int N,
                        int* __restrict__ rowptr, int* __restrict__ bsum) {
    __shared__ int lds[256];
    int t = threadIdx.x;
    int i = blockIdx.x * 256 + t;
    int v = (i < N) ? deg[i] : 0;
    lds[t] = v; __syncthreads();
    #pragma unroll
    for (int off = 1; off < 256; off <<= 1) {
        int tmp = (t >= off) ? lds[t - off] : 0; __syncthreads();
        lds[t] += tmp; __syncthreads();
    }
    if (i < N) rowptr[i] = lds[t] - v;
    if (t == 255) bsum[blockIdx.x] = lds[255];
}

__global__ void k_scan2(const int* __restrict__ bsum, int nb, int* __restrict__ boff) {
    __shared__ int lds[1024];
    int t = threadIdx.x;
    int v = (t < nb) ? bsum[t] : 0;
    lds[t] = v; __syncthreads();
    #pragma unroll
    for (int off = 1; off < 1024; off <<= 1) {
        int tmp = (t >= off) ? lds[t - off] : 0; __syncthreads();
        lds[t] += tmp; __syncthreads();
    }
    if (t < nb) boff[t] = lds[t] - v;
    if (t == 0) boff[nb] = lds[1023];
}

__global__ void k_scan3(const int* __restrict__ boff, int N, int nb,
                        int* __restrict__ rowptr, const int* __restrict__ deg,
                        float* __restrict__ dinv) {
    int i = blockIdx.x * blockDim.x + threadIdx.x;
    if (i < N) {
        rowptr[i] += boff[i >> 8];
        dinv[i] = rsqrtf((float)deg[i] + 1.0f);
    } else if (i == N) {
        rowptr[N] = boff[nb];
    }
}

// hw1[n] packed: uint f = bf16(dinv*(x*W1[0,2f]+c0)) | bf16(...2f+1)<<16
__global__ void k_layer1(const float* __restrict__ x, const float* __restrict__ delta,
                         const float* __restrict__ W1, const float* __restrict__ dinv,
                         unsigned* __restrict__ hw, int N) {
    int idx = blockIdx.x * blockDim.x + threadIdx.x;
    if (idx >= N * 32) return;
    int n = idx >> 5, f = idx & 31;
    int d0 = 2 * f, d1 = 2 * f + 1;
    float c0 = delta[0] * W1[64 + d0] + delta[1] * W1[128 + d0] +
               delta[2] * W1[192 + d0] + delta[3] * W1[256 + d0];
    float c1 = delta[0] * W1[64 + d1] + delta[1] * W1[128 + d1] +
               delta[2] * W1[192 + d1] + delta[3] * W1[256 + d1];
    float dn = dinv[n], xv = x[n];
    hw[idx] = packbf(dn * fmaf(xv, W1[d0], c0), dn * fmaf(xv, W1[d1], c1));
}

// 2-edge-per-load aggregation. lane&31 = feature pair fb, lane>>5 = edge parity.
// Returns fp32 pair accumulated over this wave-half's edges (NOT combined).
__device__ __forceinline__ void agg_pair(const unsigned* __restrict__ hw,
                                         const int* __restrict__ col,
                                         int rs, int re, int lane,
                                         float& a0, float& a1) {
    int fb = lane & 31, half = lane >> 5;
    for (int base = rs; base < re; base += 64) {
        int cnt = min(64, re - base);
        int s = (lane < cnt) ? col[base + lane] : 0;
        int j = 0;
        for (; j + 8 <= cnt; j += 8) {           // 4 loads in flight, 8 edges
            int i0 = __shfl(s, j     + half);
            int i1 = __shfl(s, j + 2 + half);
            int i2 = __shfl(s, j + 4 + half);
            int i3 = __shfl(s, j + 6 + half);
            unsigned w0 = hw[(size_t)i0 * 32 + fb];
            unsigned w1 = hw[(size_t)i1 * 32 + fb];
            unsigned w2 = hw[(size_t)i2 * 32 + fb];
            unsigned w3 = hw[(size_t)i3 * 32 + fb];
            a0 += (blo(w0) + blo(w1)) + (blo(w2) + blo(w3));
            a1 += (bhi(w0) + bhi(w1)) + (bhi(w2) + bhi(w3));
        }
        for (; j + 2 <= cnt; j += 2) {
            int i = __shfl(s, j + half);
            unsigned w = hw[(size_t)i * 32 + fb];
            a0 += blo(w); a1 += bhi(w);
        }
        if (j < cnt) {                           // odd tail: half 0 only
            int i = __shfl(s, j);                // shfl outside branch (exec!)
            if (half == 0) {
                unsigned w = hw[(size_t)i * 32 + fb];
                a0 += blo(w); a1 += bhi(w);
            }
        }
    }
}

__global__ __launch_bounds__(256, 4) void k_agg_gemm64(
    const unsigned* __restrict__ hw_in, const int* __restrict__ rowptr,
    const int* __restrict__ col, const float* __restrict__ dinv,
    const float* __restrict__ bias, const float* __restrict__ W,
    unsigned* __restrict__ hw_out, int N) {
    __shared__ float rowbuf[4][64];
    int lane = threadIdx.x & 63, wave = threadIdx.x >> 6;
    int fb = lane & 31, half = lane >> 5;
    float Wreg[64];                              // fp32 column `lane` of W
    #pragma unroll
    for (int k = 0; k < 64; ++k) Wreg[k] = W[k * 64 + lane];
    float b0 = bias[2 * fb], b1 = bias[2 * fb + 1];
    int gw = blockIdx.x * 4 + wave;
    int stride = gridDim.x * 4;
    for (int n = gw; n < N; n += stride) {
        float a0 = 0.f, a1 = 0.f;
        int rs = rowptr[n], re = rowptr[n + 1];
        agg_pair(hw_in, col, rs, re, lane, a0, a1);
        a0 += __shfl_xor(a0, 32);                // combine edge-parity halves
        a1 += __shfl_xor(a1, 32);
        unsigned sw = hw_in[(size_t)n * 32 + fb]; // self-loop
        a0 += blo(sw); a1 += bhi(sw);
        float dn = dinv[n];
        float t0 = fmaxf(fmaf(dn, a0, b0), 0.0f);
        float t1 = fmaxf(fmaf(dn, a1, b1), 0.0f);
        if (half == 0)
            *(float2*)&rowbuf[wave][2 * fb] = make_float2(t0, t1);
        __builtin_amdgcn_wave_barrier();
        float o = 0.f;
        const float4* rb = (const float4*)(&rowbuf[wave][0]);
        #pragma unroll
        for (int k4 = 0; k4 < 16; ++k4) {        // 16 broadcast ds_read_b128
            float4 tv = rb[k4];
            o = fmaf(tv.x, Wreg[4 * k4 + 0], o);
            o = fmaf(tv.y, Wreg[4 * k4 + 1], o);
            o = fmaf(tv.z, Wreg[4 * k4 + 2], o);
            o = fmaf(tv.w, Wreg[4 * k4 + 3], o);
        }
        rowbuf[wave][lane] = dn * o;             // in-order DS: safe reuse
        __builtin_amdgcn_wave_barrier();
        if (half == 0) {
            float2 ov = *(float2*)&rowbuf[wave][2 * fb];
            hw_out[(size_t)n * 32 + fb] = packbf(ov.x, ov.y);
        }
    }
}

__global__ __launch_bounds__(256, 4) void k_agg_out3(
    const unsigned* __restrict__ hw_in, const int* __restrict__ rowptr,
    const int* __restrict__ col, const float* __restrict__ dinv,
    const float* __restrict__ bias, const float* __restrict__ W3,
    float4* __restrict__ hw3, int N) {
    int lane = threadIdx.x & 63, wave = threadIdx.x >> 6;
    int fb = lane & 31;
    int d0 = 2 * fb, d1 = 2 * fb + 1;
    float wa0 = W3[d0 * 3 + 0], wa1 = W3[d0 * 3 + 1], wa2 = W3[d0 * 3 + 2];
    float wb0 = W3[d1 * 3 + 0], wb1 = W3[d1 * 3 + 1], wb2 = W3[d1 * 3 + 2];
    float b0 = bias[d0], b1 = bias[d1];
    int gw = blockIdx.x * 4 + wave;
    int stride = gridDim.x * 4;
    for (int n = gw; n < N; n += stride) {
        float a0 = 0.f, a1 = 0.f;
        int rs = rowptr[n], re = rowptr[n + 1];
        agg_pair(hw_in, col, rs, re, lane, a0, a1);
        a0 += __shfl_xor(a0, 32);
        a1 += __shfl_xor(a1, 32);
        unsigned sw = hw_in[(size_t)n * 32 + fb];
        a0 += blo(sw); a1 += bhi(sw);
        float dn = dinv[n];
        float t0 = fmaxf(fmaf(dn, a0, b0), 0.0f);
        float t1 = fmaxf(fmaf(dn, a1, b1), 0.0f);
        float p0 = fmaf(t0, wa0, t1 * wb0);
        float p1 = fmaf(t0, wa1, t1 * wb1);
        float p2 = fmaf(t0, wa2, t1 * wb2);
        #pragma unroll
        for (int off = 16; off; off >>= 1) {     // halves identical: reduce 32
            p0 += __shfl_xor(p0, off);
            p1 += __shfl_xor(p1, off);
            p2 += __shfl_xor(p2, off);
        }
        if (lane == 0) hw3[n] = make_float4(dn * p0, dn * p1, dn * p2, 0.f);
    }
}

__global__ __launch_bounds__(256) void k_final(
    const float4* __restrict__ hw3, const int* __restrict__ rowptr,
    const int* __restrict__ col, const float* __restrict__ dinv,
    const float* __restrict__ b3, const float* __restrict__ x,
    const float* __restrict__ pos, float* __restrict__ out, int N) {
    int lane = threadIdx.x & 63, wave = threadIdx.x >> 6;
    int n = blockIdx.x * 4 + wave;
    if (n >= N) return;
    int rs = rowptr[n], re = rowptr[n + 1];
    float a0 = 0.f, a1 = 0.f, a2 = 0.f;
    for (int i = rs + lane; i < re; i += 64) {
        float4 v = hw3[col[i]];
        a0 += v.x; a1 += v.y; a2 += v.z;
    }
    #pragma unroll
    for (int off = 32; off; off >>= 1) {
        a0 += __shfl_xor(a0, off);
        a1 += __shfl_xor(a1, off);
        a2 += __shfl_xor(a2, off);
    }
    if (lane == 0) {
        float4 sv = hw3[n];
        a0 += sv.x; a1 += sv.y; a2 += sv.z;
        float dn = dinv[n];
        float o0 = fmaf(dn, a0, b3[0]);
        float o1 = fmaf(dn, a1, b3[1]);
        float o2 = fmaf(dn, a2, b3[2]);
        out[n] = x[n] + o2;
        out[N + 2 * n]     = pos[2 * n]     + o0;
        out[N + 2 * n + 1] = pos[2 * n + 1] + o1;
    }
}

extern "C" void kernel_launch(void* const* d_in, const int* in_sizes, int n_in,
                              void* d_out, int out_size, void* d_ws, size_t ws_size,
                              hipStream_t stream) {
    const float* x     = (const float*)d_in[0];
    const float* pos   = (const float*)d_in[1];
    const float* delta = (const float*)d_in[2];
    const int*   ei    = (const int*)  d_in[3];
    const float* W1    = (const float*)d_in[4];
    const float* b1    = (const float*)d_in[5];
    const float* W2    = (const float*)d_in[6];
    const float* b2    = (const float*)d_in[7];
    const float* W3    = (const float*)d_in[8];
    const float* b3    = (const float*)d_in[9];
    int N = in_sizes[0];
    int E = in_sizes[3] / 2;
    const int* src = ei;
    const int* dst = ei + E;

    char* p = (char*)d_ws;
    auto alloc = [&](size_t bytes) {
        char* r = p; p += (bytes + 255) & ~(size_t)255; return r;
    };
    int*   deg    = (int*)  alloc((size_t)N * 4);
    int*   bcur   = (int*)  alloc(256 * 4);
    int*   rowptr = (int*)  alloc((size_t)(N + 1) * 4);
    int nb1 = (N + 255) / 256;
    int*   bsum   = (int*)  alloc((size_t)nb1 * 4);
    int*   boff   = (int*)  alloc((size_t)(nb1 + 1) * 4);
    float* dinv   = (float*)alloc((size_t)N * 4);
    int*   col    = (int*)  alloc((size_t)E * 4);
    unsigned* hw_a = (unsigned*)alloc((size_t)N * 32 * 4);   // bf16x2 packed
    unsigned* hw_b = (unsigned*)alloc((size_t)N * 32 * 4);

    int B   = (N + BW_ - 1) >> SHIFT;   // 196 buckets for N=100K
    int cap = 2 * (E / B) + 1024;
    unsigned* words = (unsigned*)alloc((size_t)B * cap * 4);
    float4*   hw3   = (float4*)words;   // words dead after k_place; 1.6MB fits

    int npb = (E + (256 * ITEMS) - 1) / (256 * ITEMS);

    hipMemsetAsync(bcur, 0, 256 * 4, stream);
    k_partition<<<npb, 256, 0, stream>>>(src, dst, E, bcur, words, cap);
    k_hist<<<B, 512, 0, stream>>>(words, bcur, cap, deg, N);
    k_scan1<<<nb1, 256, 0, stream>>>(deg, N, rowptr, bsum);
    k_scan2<<<1, 1024, 0, stream>>>(bsum, nb1, boff);
    k_scan3<<<(N + 256) / 256, 256, 0, stream>>>(boff, N, nb1, rowptr, deg, dinv);
    k_place<<<B, 512, 0, stream>>>(words, bcur, cap, rowptr, col, N);
    k_layer1<<<(N * 32 + 255) / 256, 256, 0, stream>>>(x, delta, W1, dinv, hw_a, N);
    k_agg_gemm64<<<2048, 256, 0, stream>>>(hw_a, rowptr, col, dinv, b1, W2, hw_b, N);
    k_agg_out3<<<2048, 256, 0, stream>>>(hw_b, rowptr, col, dinv, b2, W3, hw3, N);
    k_final<<<(N + 3) / 4, 256, 0, stream>>>(hw3, rowptr, col, dinv, b3, x, pos,
                                             (float*)d_out, N);
}

// Round 6
// 269.903 us; speedup vs baseline: 1.6907x; 1.0381x over previous
//
#include <hip/hip_runtime.h>

// GCN 3-layer (PyG GCNConv: self-loops + D^-1/2 A D^-1/2).
// R6 changes (latency regime: HBM 16%, VALU 34%, occ 38% in R5):
//  1. Wreg[64] pinned via asm "+v" (R5 VGPR=56 proved remat: ~64 L1 loads/node).
//  2. Gather in 16-edge groups -> 8 loads in flight (was 4), masked tail.
//  3. Next-node col/rowptr prefetch rotation hides col latency.

#define SHIFT 9
#define BW_ (1 << SHIFT)      // 512 nodes per bucket
#define ITEMS 16              // edges per thread in k_partition

__device__ __forceinline__ float blo(unsigned w) { return __uint_as_float(w << 16); }
__device__ __forceinline__ float bhi(unsigned w) { return __uint_as_float(w & 0xffff0000u); }
__device__ __forceinline__ unsigned packbf(float a, float b) {
    unsigned ua = __float_as_uint(a), ub = __float_as_uint(b);
    ua = (ua + 0x7fffu + ((ua >> 16) & 1u)) >> 16;         // RN-even
    ub = (ub + 0x7fffu + ((ub >> 16) & 1u)) & 0xffff0000u;
    return ua | ub;
}

__global__ __launch_bounds__(256) void k_partition(
    const int* __restrict__ src, const int* __restrict__ dst, int E,
    int* __restrict__ bcur, unsigned* __restrict__ words, int cap) {
    __shared__ int cnt[256];
    __shared__ int gbase[256];
    int t = threadIdx.x;
    int base = blockIdx.x * (256 * ITEMS);
    cnt[t] = 0;
    __syncthreads();
    unsigned w[ITEMS]; int b[ITEMS], r[ITEMS];
    #pragma unroll
    for (int j = 0; j < ITEMS; ++j) {
        int e = base + j * 256 + t;
        if (e < E) {
            int d = dst[e], s = src[e];
            b[j] = d >> SHIFT;
            w[j] = ((unsigned)s << SHIFT) | (unsigned)(d & (BW_ - 1));
            r[j] = atomicAdd(&cnt[b[j]], 1);     // LDS atomic
        } else b[j] = -1;
    }
    __syncthreads();
    int c = cnt[t];
    gbase[t] = c ? atomicAdd(&bcur[t], c) : 0;
    __syncthreads();
    #pragma unroll
    for (int j = 0; j < ITEMS; ++j) {
        if (b[j] >= 0) {
            int idx = gbase[b[j]] + r[j];
            if (idx < cap)
                words[(size_t)b[j] * cap + idx] = w[j];
        }
    }
}

__global__ __launch_bounds__(512) void k_hist(
    const unsigned* __restrict__ words, const int* __restrict__ bcnt, int cap,
    int* __restrict__ deg, int N) {
    __shared__ int h[BW_];
    int b = blockIdx.x, t = threadIdx.x;
    h[t] = 0;
    __syncthreads();
    int n = min(bcnt[b], cap);
    const unsigned* wb = words + (size_t)b * cap;
    for (int i = t; i < n; i += 512)
        atomicAdd(&h[wb[i] & (BW_ - 1)], 1);
    __syncthreads();
    int node = b * BW_ + t;
    if (node < N) deg[node] = h[t];
}

__global__ __launch_bounds__(512) void k_place(
    const unsigned* __restrict__ words, const int* __restrict__ bcnt, int cap,
    const int* __restrict__ rowptr, int* __restrict__ col, int N) {
    __shared__ int cur[BW_];
    int b = blockIdx.x, t = threadIdx.x;
    int node = b * BW_ + t;
    cur[t] = (node < N) ? rowptr[node] : 0;
    __syncthreads();
    int n = min(bcnt[b], cap);
    const unsigned* wb = words + (size_t)b * cap;
    for (int i = t; i < n; i += 512) {
        unsigned w = wb[i];
        int p = atomicAdd(&cur[w & (BW_ - 1)], 1);
        col[p] = (int)(w >> SHIFT);
    }
}

__global__ void k_scan1(const int* __restrict__ deg, int N,
                        int* __restrict__ rowptr, int* __restrict__ bsum) {
    __shared__ int lds[256];
    int t = threadIdx.x;
    int i = blockIdx.x * 256 + t;
    int v = (i < N) ? deg[i] : 0;
    lds[t] = v; __syncthreads();
    #pragma unroll
    for (int off = 1; off < 256; off <<= 1) {
        int tmp = (t >= off) ? lds[t - off] : 0; __syncthreads();
        lds[t] += tmp; __syncthreads();
    }
    if (i < N) rowptr[i] = lds[t] - v;
    if (t == 255) bsum[blockIdx.x] = lds[255];
}

__global__ void k_scan2(const int* __restrict__ bsum, int nb, int* __restrict__ boff) {
    __shared__ int lds[1024];
    int t = threadIdx.x;
    int v = (t < nb) ? bsum[t] : 0;
    lds[t] = v; __syncthreads();
    #pragma unroll
    for (int off = 1; off < 1024; off <<= 1) {
        int tmp = (t >= off) ? lds[t - off] : 0; __syncthreads();
        lds[t] += tmp; __syncthreads();
    }
    if (t < nb) boff[t] = lds[t] - v;
    if (t == 0) boff[nb] = lds[1023];
}

__global__ void k_scan3(const int* __restrict__ boff, int N, int nb,
                        int* __restrict__ rowptr, const int* __restrict__ deg,
                        float* __restrict__ dinv) {
    int i = blockIdx.x * blockDim.x + threadIdx.x;
    if (i < N) {
        rowptr[i] += boff[i >> 8];
        dinv[i] = rsqrtf((float)deg[i] + 1.0f);
    } else if (i == N) {
        rowptr[N] = boff[nb];
    }
}

// hw1[n] packed: uint f = bf16(dinv*(x*W1[0,2f]+c0)) | bf16(...2f+1)<<16
__global__ void k_layer1(const float* __restrict__ x, const float* __restrict__ delta,
                         const float* __restrict__ W1, const float* __restrict__ dinv,
                         unsigned* __restrict__ hw, int N) {
    int idx = blockIdx.x * blockDim.x + threadIdx.x;
    if (idx >= N * 32) return;
    int n = idx >> 5, f = idx & 31;
    int d0 = 2 * f, d1 = 2 * f + 1;
    float c0 = delta[0] * W1[64 + d0] + delta[1] * W1[128 + d0] +
               delta[2] * W1[192 + d0] + delta[3] * W1[256 + d0];
    float c1 = delta[0] * W1[64 + d1] + delta[1] * W1[128 + d1] +
               delta[2] * W1[192 + d1] + delta[3] * W1[256 + d1];
    float dn = dinv[n], xv = x[n];
    hw[idx] = packbf(dn * fmaf(xv, W1[d0], c0), dn * fmaf(xv, W1[d1], c1));
}

// Gather one <=64-edge chunk, 16 edges per group (8 loads in flight).
// Invalid slots clamped to a valid index and masked to 0 (blo(0)=bhi(0)=0).
__device__ __forceinline__ void gather16(const unsigned* __restrict__ hw,
                                         int s, int cnt, int fb, int half,
                                         float& a0, float& a1) {
    for (int j = 0; j < cnt; j += 16) {
        unsigned v[8]; int e[8];
        #pragma unroll
        for (int g = 0; g < 8; ++g) {
            e[g] = j + 2 * g + half;
            int idx = __shfl(s, min(e[g], cnt - 1));
            v[g] = hw[(size_t)idx * 32 + fb];
        }
        #pragma unroll
        for (int g = 0; g < 8; ++g) {
            unsigned w = (e[g] < cnt) ? v[g] : 0u;
            a0 += blo(w); a1 += bhi(w);
        }
    }
}

__global__ __launch_bounds__(256, 4) void k_agg_gemm64(
    const unsigned* __restrict__ hw_in, const int* __restrict__ rowptr,
    const int* __restrict__ col, const float* __restrict__ dinv,
    const float* __restrict__ bias, const float* __restrict__ W,
    unsigned* __restrict__ hw_out, int N) {
    __shared__ float rowbuf[4][64];
    int lane = threadIdx.x & 63, wave = threadIdx.x >> 6;
    int fb = lane & 31, half = lane >> 5;
    float Wreg[64];                              // fp32 column `lane` of W
    #pragma unroll
    for (int k = 0; k < 64; ++k) Wreg[k] = W[k * 64 + lane];
    #pragma unroll
    for (int k = 0; k < 64; ++k) asm volatile("" : "+v"(Wreg[k]));  // pin: no remat
    float b0 = bias[2 * fb], b1 = bias[2 * fb + 1];
    int stride = gridDim.x * 4;
    int n = blockIdx.x * 4 + wave;
    // prologue: prefetch first node's row meta + col chunk
    int rs = 0, re = 0;
    if (n < N) { rs = rowptr[n]; re = rowptr[n + 1]; }
    int cnt0 = min(64, re - rs);
    int s = (cnt0 > 0) ? col[rs + min(lane, cnt0 - 1)] : 0;
    while (n < N) {
        int n2 = n + stride;
        int rs2 = 0, re2 = 0;
        if (n2 < N) { rs2 = rowptr[n2]; re2 = rowptr[n2 + 1]; }
        int cnt2 = min(64, re2 - rs2);
        int s2 = (cnt2 > 0) ? col[rs2 + min(lane, cnt2 - 1)] : 0;  // prefetch next
        unsigned sw = hw_in[(size_t)n * 32 + fb];                  // self-loop
        float a0 = 0.f, a1 = 0.f;
        gather16(hw_in, s, cnt0, fb, half, a0, a1);
        for (int base = rs + 64; base < re; base += 64) {          // rare: deg>64
            int cc = min(64, re - base);
            int sx = col[base + min(lane, cc - 1)];
            gather16(hw_in, sx, cc, fb, half, a0, a1);
        }
        a0 += __shfl_xor(a0, 32);                // combine edge-parity halves
        a1 += __shfl_xor(a1, 32);
        a0 += blo(sw); a1 += bhi(sw);
        float dn = dinv[n];
        float t0 = fmaxf(fmaf(dn, a0, b0), 0.0f);
        float t1 = fmaxf(fmaf(dn, a1, b1), 0.0f);
        if (half == 0)
            *(float2*)&rowbuf[wave][2 * fb] = make_float2(t0, t1);
        __builtin_amdgcn_wave_barrier();
        float o = 0.f;
        const float4* rb = (const float4*)(&rowbuf[wave][0]);
        #pragma unroll
        for (int k4 = 0; k4 < 16; ++k4) {        // 16 broadcast ds_read_b128
            float4 tv = rb[k4];
            o = fmaf(tv.x, Wreg[4 * k4 + 0], o);
            o = fmaf(tv.y, Wreg[4 * k4 + 1], o);
            o = fmaf(tv.z, Wreg[4 * k4 + 2], o);
            o = fmaf(tv.w, Wreg[4 * k4 + 3], o);
        }
        rowbuf[wave][lane] = dinv[n] * o;        // in-order DS: safe reuse
        __builtin_amdgcn_wave_barrier();
        if (half == 0) {
            float2 ov = *(float2*)&rowbuf[wave][2 * fb];
            hw_out[(size_t)n * 32 + fb] = packbf(ov.x, ov.y);
        }
        n = n2; rs = rs2; re = re2; cnt0 = cnt2; s = s2;  // rotate pipeline
    }
}

__global__ __launch_bounds__(256, 4) void k_agg_out3(
    const unsigned* __restrict__ hw_in, const int* __restrict__ rowptr,
    const int* __restrict__ col, const float* __restrict__ dinv,
    const float* __restrict__ bias, const float* __restrict__ W3,
    float4* __restrict__ hw3, int N) {
    int lane = threadIdx.x & 63, wave = threadIdx.x >> 6;
    int fb = lane & 31, half = lane >> 5;
    int d0 = 2 * fb, d1 = 2 * fb + 1;
    float wa0 = W3[d0 * 3 + 0], wa1 = W3[d0 * 3 + 1], wa2 = W3[d0 * 3 + 2];
    float wb0 = W3[d1 * 3 + 0], wb1 = W3[d1 * 3 + 1], wb2 = W3[d1 * 3 + 2];
    float b0 = bias[d0], b1 = bias[d1];
    int stride = gridDim.x * 4;
    int n = blockIdx.x * 4 + wave;
    int rs = 0, re = 0;
    if (n < N) { rs = rowptr[n]; re = rowptr[n + 1]; }
    int cnt0 = min(64, re - rs);
    int s = (cnt0 > 0) ? col[rs + min(lane, cnt0 - 1)] : 0;
    while (n < N) {
        int n2 = n + stride;
        int rs2 = 0, re2 = 0;
        if (n2 < N) { rs2 = rowptr[n2]; re2 = rowptr[n2 + 1]; }
        int cnt2 = min(64, re2 - rs2);
        int s2 = (cnt2 > 0) ? col[rs2 + min(lane, cnt2 - 1)] : 0;
        unsigned sw = hw_in[(size_t)n * 32 + fb];
        float a0 = 0.f, a1 = 0.f;
        gather16(hw_in, s, cnt0, fb, half, a0, a1);
        for (int base = rs + 64; base < re; base += 64) {
            int cc = min(64, re - base);
            int sx = col[base + min(lane, cc - 1)];
            gather16(hw_in, sx, cc, fb, half, a0, a1);
        }
        a0 += __shfl_xor(a0, 32);
        a1 += __shfl_xor(a1, 32);
        a0 += blo(sw); a1 += bhi(sw);
        float dn = dinv[n];
        float t0 = fmaxf(fmaf(dn, a0, b0), 0.0f);
        float t1 = fmaxf(fmaf(dn, a1, b1), 0.0f);
        float p0 = fmaf(t0, wa0, t1 * wb0);
        float p1 = fmaf(t0, wa1, t1 * wb1);
        float p2 = fmaf(t0, wa2, t1 * wb2);
        #pragma unroll
        for (int off = 16; off; off >>= 1) {     // halves identical: reduce 32
            p0 += __shfl_xor(p0, off);
            p1 += __shfl_xor(p1, off);
            p2 += __shfl_xor(p2, off);
        }
        if (lane == 0) hw3[n] = make_float4(dn * p0, dn * p1, dn * p2, 0.f);
        n = n2; rs = rs2; re = re2; cnt0 = cnt2; s = s2;
    }
}

__global__ __launch_bounds__(256) void k_final(
    const float4* __restrict__ hw3, const int* __restrict__ rowptr,
    const int* __restrict__ col, const float* __restrict__ dinv,
    const float* __restrict__ b3, const float* __restrict__ x,
    const float* __restrict__ pos, float* __restrict__ out, int N) {
    int lane = threadIdx.x & 63, wave = threadIdx.x >> 6;
    int n = blockIdx.x * 4 + wave;
    if (n >= N) return;
    int rs = rowptr[n], re = rowptr[n + 1];
    float a0 = 0.f, a1 = 0.f, a2 = 0.f;
    for (int i = rs + lane; i < re; i += 64) {
        float4 v = hw3[col[i]];
        a0 += v.x; a1 += v.y; a2 += v.z;
    }
    #pragma unroll
    for (int off = 32; off; off >>= 1) {
        a0 += __shfl_xor(a0, off);
        a1 += __shfl_xor(a1, off);
        a2 += __shfl_xor(a2, off);
    }
    if (lane == 0) {
        float4 sv = hw3[n];
        a0 += sv.x; a1 += sv.y; a2 += sv.z;
        float dn = dinv[n];
        float o0 = fmaf(dn, a0, b3[0]);
        float o1 = fmaf(dn, a1, b3[1]);
        float o2 = fmaf(dn, a2, b3[2]);
        out[n] = x[n] + o2;
        out[N + 2 * n]     = pos[2 * n]     + o0;
        out[N + 2 * n + 1] = pos[2 * n + 1] + o1;
    }
}

extern "C" void kernel_launch(void* const* d_in, const int* in_sizes, int n_in,
                              void* d_out, int out_size, void* d_ws, size_t ws_size,
                              hipStream_t stream) {
    const float* x     = (const float*)d_in[0];
    const float* pos   = (const float*)d_in[1];
    const float* delta = (const float*)d_in[2];
    const int*   ei    = (const int*)  d_in[3];
    const float* W1    = (const float*)d_in[4];
    const float* b1    = (const float*)d_in[5];
    const float* W2    = (const float*)d_in[6];
    const float* b2    = (const float*)d_in[7];
    const float* W3    = (const float*)d_in[8];
    const float* b3    = (const float*)d_in[9];
    int N = in_sizes[0];
    int E = in_sizes[3] / 2;
    const int* src = ei;
    const int* dst = ei + E;

    char* p = (char*)d_ws;
    auto alloc = [&](size_t bytes) {
        char* r = p; p += (bytes + 255) & ~(size_t)255; return r;
    };
    int*   deg    = (int*)  alloc((size_t)N * 4);
    int*   bcur   = (int*)  alloc(256 * 4);
    int*   rowptr = (int*)  alloc((size_t)(N + 1) * 4);
    int nb1 = (N + 255) / 256;
    int*   bsum   = (int*)  alloc((size_t)nb1 * 4);
    int*   boff   = (int*)  alloc((size_t)(nb1 + 1) * 4);
    float* dinv   = (float*)alloc((size_t)N * 4);
    int*   col    = (int*)  alloc((size_t)E * 4);
    unsigned* hw_a = (unsigned*)alloc((size_t)N * 32 * 4);   // bf16x2 packed
    unsigned* hw_b = (unsigned*)alloc((size_t)N * 32 * 4);

    int B   = (N + BW_ - 1) >> SHIFT;   // 196 buckets for N=100K
    int cap = 2 * (E / B) + 1024;
    unsigned* words = (unsigned*)alloc((size_t)B * cap * 4);
    float4*   hw3   = (float4*)words;   // words dead after k_place; 1.6MB fits

    int npb = (E + (256 * ITEMS) - 1) / (256 * ITEMS);

    hipMemsetAsync(bcur, 0, 256 * 4, stream);
    k_partition<<<npb, 256, 0, stream>>>(src, dst, E, bcur, words, cap);
    k_hist<<<B, 512, 0, stream>>>(words, bcur, cap, deg, N);
    k_scan1<<<nb1, 256, 0, stream>>>(deg, N, rowptr, bsum);
    k_scan2<<<1, 1024, 0, stream>>>(bsum, nb1, boff);
    k_scan3<<<(N + 256) / 256, 256, 0, stream>>>(boff, N, nb1, rowptr, deg, dinv);
    k_place<<<B, 512, 0, stream>>>(words, bcur, cap, rowptr, col, N);
    k_layer1<<<(N * 32 + 255) / 256, 256, 0, stream>>>(x, delta, W1, dinv, hw_a, N);
    k_agg_gemm64<<<2048, 256, 0, stream>>>(hw_a, rowptr, col, dinv, b1, W2, hw_b, N);
    k_agg_out3<<<2048, 256, 0, stream>>>(hw_b, rowptr, col, dinv, b2, W3, hw3, N);
    k_final<<<(N + 3) / 4, 256, 0, stream>>>(hw3, rowptr, col, dinv, b3, x, pos,
                                             (float*)d_out, N);
}